// Round 1
// baseline (19088.535 us; speedup 1.0000x reference)
//
#include <hip/hip_runtime.h>

#define NB 8
#define T 32000
#define NLAYERS 30
#define RES 64
#define GATE 128
#define SKIPC 64
#define CIN 80
#define OUTC 256
#define TF 400
#define TM 4000

// packed weight layout per layer: conv [i:64][tap:2][o:128] = 16384, cond [i:80][o:128] = 10240
#define LSTRIDE 26624
#define L1T_OFF (NLAYERS * LSTRIDE)
#define PACK_FLOATS (L1T_OFF + 4096)

__global__ void pack_weights(const float* __restrict__ conv_w,
                             const float* __restrict__ cond_w,
                             const float* __restrict__ last1_w,
                             float* __restrict__ wp) {
    int e = blockIdx.x * 256 + threadIdx.x;
    if (e >= PACK_FLOATS) return;
    if (e < NLAYERS * LSTRIDE) {
        int l = e / LSTRIDE, r = e % LSTRIDE;
        if (r < 16384) {
            int i = r >> 8, tap = (r >> 7) & 1, o = r & 127;
            wp[e] = conv_w[((l * GATE + o) * RES + i) * 2 + tap];
        } else {
            int r2 = r - 16384;
            int i = r2 >> 7, o = r2 & 127;
            wp[e] = cond_w[(l * GATE + o) * CIN + i];
        }
    } else {
        int r = e - NLAYERS * LSTRIDE;
        int i = r >> 6, o = r & 63;
        wp[e] = last1_w[o * 64 + i];   // transposed [i][o]
    }
}

// h[b,o,t] = first_w[o, x[b,t]] + first_b[o]
__global__ void first_conv(const int* __restrict__ x, const float* __restrict__ fw,
                           const float* __restrict__ fb, float* __restrict__ h) {
    int tid = blockIdx.x * 256 + threadIdx.x;   // NB*T threads
    int b = tid / T, t = tid - b * T;
    int idx = x[tid];
    int base = (b * RES) * T + t;
    for (int o = 0; o < RES; ++o)
        h[base + o * T] = fw[o * OUTC + idx] + fb[o];
}

// c1 = cin_w @ condition  [8,80,400]
__global__ void cond_in(const float* __restrict__ cond, const float* __restrict__ cw,
                        float* __restrict__ c1) {
    int tid = blockIdx.x * blockDim.x + threadIdx.x;
    if (tid >= NB * TF) return;
    int b = tid / TF, t = tid - b * TF;
    float in[CIN];
#pragma unroll
    for (int i = 0; i < CIN; ++i) in[i] = cond[(b * CIN + i) * TF + t];
    for (int o = 0; o < CIN; ++o) {
        float acc = 0.f;
#pragma unroll
        for (int i = 0; i < CIN; ++i) acc += cw[o * CIN + i] * in[i];
        c1[(b * CIN + o) * TF + t] = acc;
    }
}

// repeat x10 then 21-tap avg with zero pad: [.,400] -> [.,4000]
__global__ void up1(const float* __restrict__ src, float* __restrict__ dst) {
    int tid = blockIdx.x * 256 + threadIdx.x;   // NB*CIN*TM
    int t = tid % TM, rc = tid / TM;
    const float* s = src + rc * TF;
    float acc = 0.f;
#pragma unroll
    for (int k = -10; k <= 10; ++k) {
        int j = t + k;
        if (j >= 0 && j < TM) acc += s[j / 10];
    }
    dst[tid] = acc * (1.f / 21.f);
}

// repeat x8 then 17-tap avg with zero pad: [.,4000] -> [.,32000]
__global__ void up2(const float* __restrict__ src, float* __restrict__ dst) {
    int tid = blockIdx.x * 256 + threadIdx.x;   // NB*CIN*T
    int t = tid % T, rc = tid / T;
    const float* s = src + rc * TM;
    float acc = 0.f;
#pragma unroll
    for (int k = -8; k <= 8; ++k) {
        int j = t + k;
        if (j >= 0 && j < T) acc += s[j >> 3];
    }
    dst[tid] = acc * (1.f / 17.f);
}

__global__ __launch_bounds__(256, 2)
void layer_k(const float* __restrict__ h_in, float* __restrict__ h_out,
             float* __restrict__ skips, const float* __restrict__ c,
             const float* __restrict__ wp, const float* __restrict__ conv_b,
             const float* __restrict__ skip_w, const float* __restrict__ skip_b,
             const float* __restrict__ out_w, const float* __restrict__ out_b,
             int l, int d, int first) {
    int tid = blockIdx.x * 256 + threadIdx.x;   // NB*T threads
    int b = tid / T, t = tid - b * T;
    const float* wl = wp + l * LSTRIDE;
    int hbase = (b * RES) * T + t;
    int cbase = (b * CIN) * T + t;
    const float* cb = conv_b + l * GATE;

    float g[GATE];
#pragma unroll
    for (int o = 0; o < GATE; ++o) g[o] = cb[o];

    // dilated 2-tap conv: tap0 -> h[t-d], tap1 -> h[t]
    for (int i = 0; i < RES; ++i) {
        float a1 = h_in[hbase + i * T];
        float a0 = (t >= d) ? h_in[hbase + i * T - d] : 0.f;
        const float* w = wl + i * 256;
#pragma unroll
        for (int o = 0; o < GATE; ++o) g[o] += w[o] * a0;
#pragma unroll
        for (int o = 0; o < GATE; ++o) g[o] += w[128 + o] * a1;
    }
    // local conditioning
    const float* cwl = wl + 16384;
    for (int i = 0; i < CIN; ++i) {
        float ci = c[cbase + i * T];
        const float* w = cwl + i * 128;
#pragma unroll
        for (int o = 0; o < GATE; ++o) g[o] += w[o] * ci;
    }
    // gating: z = tanh(a) * sigmoid(b)
    float z[SKIPC];
#pragma unroll
    for (int o = 0; o < SKIPC; ++o) {
        float a = g[o], bb = g[o + 64];
        a = fminf(fmaxf(a, -15.f), 15.f);
        bb = fminf(fmaxf(bb, -30.f), 30.f);
        float e2 = __expf(2.f * a);
        float th = (e2 - 1.f) / (e2 + 1.f);
        float sg = 1.f / (1.f + __expf(-bb));
        z[o] = th * sg;
    }
    // skip + residual projections
    const float* sb = skip_b + l * SKIPC;
    const float* ob = out_b + l * RES;
    int sbase = (b * SKIPC) * T + t;
    for (int o = 0; o < SKIPC; ++o) {
        const float* sw = skip_w + (l * SKIPC + o) * 64;
        const float* ow = out_w + (l * RES + o) * 64;
        float sacc = sb[o];
        float hacc = ob[o] + h_in[hbase + o * T];
#pragma unroll
        for (int i = 0; i < 64; ++i) sacc += sw[i] * z[i];
#pragma unroll
        for (int i = 0; i < 64; ++i) hacc += ow[i] * z[i];
        int so = sbase + o * T;
        if (first) skips[so] = sacc;
        else       skips[so] += sacc;
        h_out[hbase + o * T] = hacc;
    }
}

__global__ __launch_bounds__(256, 2)
void final_k(const float* __restrict__ skips, const float* __restrict__ wp,
             const float* __restrict__ b1, const float* __restrict__ l2w,
             const float* __restrict__ b2, float* __restrict__ out) {
    int tid = blockIdx.x * 256 + threadIdx.x;   // NB*T threads
    int b = tid / T, t = tid - b * T;
    const float* l1T = wp + L1T_OFF;
    int sbase = (b * SKIPC) * T + t;
    float y1[64];
#pragma unroll
    for (int o = 0; o < 64; ++o) y1[o] = b1[o];
    for (int i = 0; i < 64; ++i) {
        float s = fmaxf(skips[sbase + i * T], 0.f);
        const float* w = l1T + i * 64;
#pragma unroll
        for (int o = 0; o < 64; ++o) y1[o] += w[o] * s;
    }
#pragma unroll
    for (int o = 0; o < 64; ++o) y1[o] = fmaxf(y1[o], 0.f);
    int obase = (b * OUTC) * T + t;
    for (int o2 = 0; o2 < OUTC; ++o2) {
        const float* w = l2w + o2 * 64;
        float acc = b2[o2];
#pragma unroll
        for (int i = 0; i < 64; ++i) acc += w[i] * y1[i];
        out[obase + o2 * T] = acc;
    }
}

extern "C" void kernel_launch(void* const* d_in, const int* in_sizes, int n_in,
                              void* d_out, int out_size, void* d_ws, size_t ws_size,
                              hipStream_t stream) {
    const int*   x       = (const int*)  d_in[0];
    const float* cond    = (const float*)d_in[1];
    const float* first_w = (const float*)d_in[2];
    const float* first_b = (const float*)d_in[3];
    const float* cin_w   = (const float*)d_in[4];
    const float* conv_w  = (const float*)d_in[5];
    const float* conv_b  = (const float*)d_in[6];
    const float* cond_w  = (const float*)d_in[7];
    const float* skip_w  = (const float*)d_in[8];
    const float* skip_b  = (const float*)d_in[9];
    const float* out_w   = (const float*)d_in[10];
    const float* out_b   = (const float*)d_in[11];
    const float* last1_w = (const float*)d_in[12];
    const float* last1_b = (const float*)d_in[13];
    const float* last2_w = (const float*)d_in[14];
    const float* last2_b = (const float*)d_in[15];
    float* out = (float*)d_out;

    // workspace layout (floats): skips | c | c2 | c1 | wpack   (~162 MB)
    float* ws    = (float*)d_ws;
    float* skips = ws;                                  // NB*SKIPC*T = 16,384,000
    float* c     = skips + NB * SKIPC * T;              // NB*CIN*T   = 20,480,000
    float* c2    = c     + NB * CIN * T;                // NB*CIN*TM  =  2,560,000
    float* c1    = c2    + NB * CIN * TM;               // NB*CIN*TF  =    256,000
    float* wpack = c1    + NB * CIN * TF;               // PACK_FLOATS=    802,816

    // h double-buffer lives inside d_out (unused until final_k overwrites all of it)
    float* hA = out;
    float* hB = out + NB * RES * T;

    pack_weights<<<(PACK_FLOATS + 255) / 256, 256, 0, stream>>>(conv_w, cond_w, last1_w, wpack);
    first_conv<<<(NB * T) / 256, 256, 0, stream>>>(x, first_w, first_b, hA);
    cond_in<<<(NB * TF + 255) / 256, 256, 0, stream>>>(cond, cin_w, c1);
    up1<<<(NB * CIN * TM) / 256, 256, 0, stream>>>(c1, c2);
    up2<<<(NB * CIN * T) / 256, 256, 0, stream>>>(c2, c);

    for (int l = 0; l < NLAYERS; ++l) {
        int d = 1 << (l % 10);
        const float* h_in = (l & 1) ? hB : hA;
        float*       h_out = (l & 1) ? hA : hB;
        layer_k<<<(NB * T) / 256, 256, 0, stream>>>(h_in, h_out, skips, c, wpack,
                                                    conv_b, skip_w, skip_b, out_w, out_b,
                                                    l, d, (l == 0) ? 1 : 0);
    }
    final_k<<<(NB * T) / 256, 256, 0, stream>>>(skips, wpack, last1_b, last2_w, last2_b, out);
}